// Round 2
// baseline (503.219 us; speedup 1.0000x reference)
//
#include <hip/hip_runtime.h>

#define NPTS 8192
#define NB 4
#define NQ 8192

// ---------- monotone float<->uint key for atomic max over floats ----------
__device__ __forceinline__ unsigned fkey(float f) {
  unsigned u = __float_as_uint(f);
  return (u & 0x80000000u) ? ~u : (u | 0x80000000u);
}
__device__ __forceinline__ float funkey(unsigned k) {
  unsigned u = (k & 0x80000000u) ? (k & 0x7fffffffu) : ~k;
  return __uint_as_float(u);
}

// ---------- init gmax keys to 0 (== most-negative key) ----------
__global__ void k_init(unsigned* __restrict__ g) {
  g[blockIdx.x * 256 + threadIdx.x] = 0u;
}

// ---------- local encoder: lfT[b][n][128] = relu(W2 relu(W1 p + b1) + b2) ----------
__global__ __launch_bounds__(256) void k_local(const float* __restrict__ pc,
    const float* __restrict__ W1, const float* __restrict__ b1,
    const float* __restrict__ W2, const float* __restrict__ b2,
    float* __restrict__ lfT) {
  __shared__ float sW1[192], sb1[64], sW2[8192], sb2[128];
  int t = threadIdx.x;
  if (t < 192) sW1[t] = W1[t];
  if (t < 64) sb1[t] = b1[t];
  if (t < 128) sb2[t] = b2[t];
  for (int i = t; i < 8192; i += 256) sW2[i] = W2[i];
  __syncthreads();

  int gid = blockIdx.x * 256 + t;        // b*N + n
  int b = gid >> 13;
  int n = gid & 8191;
  const float* base = pc + (size_t)b * 3 * NPTS + n;
  float x = base[0], y = base[NPTS], z = base[2 * NPTS];

  float h[64];
#pragma unroll
  for (int j = 0; j < 64; ++j) {
    float v = fmaf(sW1[j * 3 + 2], z, fmaf(sW1[j * 3 + 1], y, fmaf(sW1[j * 3], x, sb1[j])));
    h[j] = fmaxf(v, 0.f);
  }

  float* o = lfT + (size_t)gid * 128;
  for (int c = 0; c < 128; c += 4) {
    float a0 = sb2[c], a1 = sb2[c + 1], a2 = sb2[c + 2], a3 = sb2[c + 3];
#pragma unroll
    for (int j = 0; j < 64; j += 4) {
      float4 w0 = *(const float4*)&sW2[(c + 0) * 64 + j];
      float4 w1 = *(const float4*)&sW2[(c + 1) * 64 + j];
      float4 w2 = *(const float4*)&sW2[(c + 2) * 64 + j];
      float4 w3 = *(const float4*)&sW2[(c + 3) * 64 + j];
      a0 = fmaf(w0.x, h[j], fmaf(w0.y, h[j + 1], fmaf(w0.z, h[j + 2], fmaf(w0.w, h[j + 3], a0))));
      a1 = fmaf(w1.x, h[j], fmaf(w1.y, h[j + 1], fmaf(w1.z, h[j + 2], fmaf(w1.w, h[j + 3], a1))));
      a2 = fmaf(w2.x, h[j], fmaf(w2.y, h[j + 1], fmaf(w2.z, h[j + 2], fmaf(w2.w, h[j + 3], a2))));
      a3 = fmaf(w3.x, h[j], fmaf(w3.y, h[j + 1], fmaf(w3.z, h[j + 2], fmaf(w3.w, h[j + 3], a3))));
    }
    float4 r;
    r.x = fmaxf(a0, 0.f); r.y = fmaxf(a1, 0.f); r.z = fmaxf(a2, 0.f); r.w = fmaxf(a3, 0.f);
    *(float4*)&o[c] = r;
  }
}

// ---------- tiled f32 GEMM: C[M x Nw] = A[M x K] * Bw[Nw x K]^T (+bias, relu) ----------
// STORE_C=true: write relu(C+bias). STORE_C=false: column-max epilogue -> gmaxK.
template <bool STORE_C>
__global__ __launch_bounds__(256) void k_gemm(const float* __restrict__ A,
    const float* __restrict__ Bw, const float* __restrict__ bias,
    float* __restrict__ C, unsigned* __restrict__ gmaxK, int Kdim, int Nw) {
  __shared__ float As[32][132];
  __shared__ float Bs[32][132];
  __shared__ unsigned smax[128];
  int t = threadIdx.x;
  int mBase = blockIdx.x * 128;
  int nBase = blockIdx.y * 128;
  int tx = t & 15, ty = t >> 4;
  float acc[8][8] = {};
  if (!STORE_C && t < 128) smax[t] = 0u;

  for (int kc = 0; kc < Kdim; kc += 32) {
    __syncthreads();
#pragma unroll
    for (int i = 0; i < 4; ++i) {
      int idx = t + i * 256;          // 0..1023
      int r = idx >> 3;               // row/col 0..127
      int k4 = (idx & 7) << 2;        // 0,4,...,28
      float4 v = *(const float4*)(A + (size_t)(mBase + r) * Kdim + kc + k4);
      As[k4 + 0][r] = v.x; As[k4 + 1][r] = v.y; As[k4 + 2][r] = v.z; As[k4 + 3][r] = v.w;
      float4 w = *(const float4*)(Bw + (size_t)(nBase + r) * Kdim + kc + k4);
      Bs[k4 + 0][r] = w.x; Bs[k4 + 1][r] = w.y; Bs[k4 + 2][r] = w.z; Bs[k4 + 3][r] = w.w;
    }
    __syncthreads();
#pragma unroll
    for (int kk = 0; kk < 32; ++kk) {
      float a[8], bv[8];
      *(float4*)&a[0] = *(const float4*)&As[kk][ty * 8];
      *(float4*)&a[4] = *(const float4*)&As[kk][ty * 8 + 4];
      *(float4*)&bv[0] = *(const float4*)&Bs[kk][tx * 8];
      *(float4*)&bv[4] = *(const float4*)&Bs[kk][tx * 8 + 4];
#pragma unroll
      for (int i = 0; i < 8; ++i)
#pragma unroll
        for (int j = 0; j < 8; ++j)
          acc[i][j] = fmaf(a[i], bv[j], acc[i][j]);
    }
  }

  if (STORE_C) {
    float bb[8];
#pragma unroll
    for (int j = 0; j < 8; ++j) bb[j] = bias[nBase + tx * 8 + j];
#pragma unroll
    for (int i = 0; i < 8; ++i) {
      float* dst = C + (size_t)(mBase + ty * 8 + i) * Nw + nBase + tx * 8;
      float r[8];
#pragma unroll
      for (int j = 0; j < 8; ++j) r[j] = fmaxf(acc[i][j] + bb[j], 0.f);
      *(float4*)dst = *(float4*)&r[0];
      *(float4*)(dst + 4) = *(float4*)&r[4];
    }
  } else {
#pragma unroll
    for (int j = 0; j < 8; ++j) {
      float cm = acc[0][j];
#pragma unroll
      for (int i = 1; i < 8; ++i) cm = fmaxf(cm, acc[i][j]);
      cm += bias[nBase + tx * 8 + j];   // bias constant per column: max(v)+b == max(v+b)
      atomicMax(&smax[tx * 8 + j], fkey(cm));
    }
    __syncthreads();
    if (t < 128) {
      int bIdx = mBase >> 13;           // rows are b*8192+n, 128 | 8192
      atomicMax(&gmaxK[bIdx * 1024 + nBase + t], smax[t]);
    }
  }
}

// ---------- KNN phase A: per (b, 256-query block, candidate chunk of 2048) top-3 ----------
// f64 difference-form distances: reproduces the true (np-f64) ordering; rel err ~1e-16.
__global__ __launch_bounds__(256) void k_knn(const float* __restrict__ pc,
    const float* __restrict__ qp, double* __restrict__ pd, int* __restrict__ pi) {
  __shared__ float4 pts[2048];
  int bid = blockIdx.x;
  int cc = bid & 3, qb = (bid >> 2) & 31, b = bid >> 7;
  int t = threadIdx.x;
  int n0 = cc * 2048;
  const float* pb = pc + (size_t)b * 3 * NPTS;
  for (int i = t; i < 2048; i += 256) {
    float x = pb[n0 + i], y = pb[NPTS + n0 + i], z = pb[2 * NPTS + n0 + i];
    pts[i] = make_float4(x, y, z, 0.f);
  }
  __syncthreads();

  int m = qb * 256 + t;
  const float* qbase = qp + (size_t)b * 3 * NPTS;
  double qx = (double)qbase[m];
  double qy = (double)qbase[NPTS + m];
  double qz = (double)qbase[2 * NPTS + m];

  double d0 = 1e300, d1 = 1e300, d2v = 1e300;
  int i0 = 0, i1 = 0, i2 = 0;
  for (int i = 0; i < 2048; ++i) {
    float4 p = pts[i];
    double dx = qx - (double)p.x;
    double dy = qy - (double)p.y;
    double dz = qz - (double)p.z;
    double d = fma(dx, dx, fma(dy, dy, dz * dz));
    if (d < d2v) {                       // strict <: earliest index wins ties (top_k stable)
      int n = n0 + i;
      if (d < d1) {
        d2v = d1; i2 = i1;
        if (d < d0) { d1 = d0; i1 = i0; d0 = d; i0 = n; }
        else       { d1 = d;  i1 = n; }
      } else { d2v = d; i2 = n; }
    }
  }
  int q = b * NQ + m;
  double* pdq = pd + (size_t)q * 12 + cc * 3;
  int* piq = pi + (size_t)q * 12 + cc * 3;
  pdq[0] = d0; pdq[1] = d1; pdq[2] = d2v;
  piq[0] = i0; piq[1] = i1; piq[2] = i2;
}

// ---------- KNN phase B: merge 4 chunk-partials (in index order -> stable) ----------
__global__ __launch_bounds__(256) void k_merge(const double* __restrict__ pd,
    const int* __restrict__ pi, int* __restrict__ ids) {
  int q = blockIdx.x * 256 + threadIdx.x;
  double d0 = 1e300, d1 = 1e300, d2v = 1e300;
  int i0 = 0, i1 = 0, i2 = 0;
#pragma unroll
  for (int j = 0; j < 12; ++j) {
    double d = pd[(size_t)q * 12 + j];
    int n = pi[(size_t)q * 12 + j];
    if (d < d2v) {
      if (d < d1) {
        d2v = d1; i2 = i1;
        if (d < d0) { d1 = d0; i1 = i0; d0 = d; i0 = n; }
        else       { d1 = d;  i1 = n; }
      } else { d2v = d; i2 = n; }
    }
  }
  ids[q * 4 + 0] = i0; ids[q * 4 + 1] = i1; ids[q * 4 + 2] = i2;
}

// ---------- broadcast gmax into out channels [0,1024) ----------
__global__ __launch_bounds__(256) void k_bcast(const unsigned* __restrict__ gmaxK,
                                               float* __restrict__ out) {
  int id = blockIdx.x * 256 + threadIdx.x;   // float4 index, 0..8388607
  int m4 = id & 2047;
  int c = (id >> 11) & 1023;
  int b = id >> 21;
  float v = funkey(gmaxK[b * 1024 + c]);
  *(float4*)(out + ((size_t)(b * 1152 + c) << 13) + (m4 << 2)) = make_float4(v, v, v, v);
}

// ---------- gather: out channels [1024,1152) = mean of 3 NN local feats ----------
__global__ __launch_bounds__(256) void k_gather(const float* __restrict__ lfT,
    const int* __restrict__ ids, float* __restrict__ out) {
  int bid = blockIdx.x;
  int b = bid >> 7, mb = bid & 127;
  int t = threadIdx.x;
  int m = mb * 64 + (t & 63);
  int cg = t >> 6;                       // 0..3 -> 32 channels each
  int q = b * NQ + m;
  int ia = ids[q * 4 + 0], ib = ids[q * 4 + 1], ic = ids[q * 4 + 2];
  const float* f0 = lfT + ((size_t)b * NPTS + ia) * 128;
  const float* f1 = lfT + ((size_t)b * NPTS + ib) * 128;
  const float* f2 = lfT + ((size_t)b * NPTS + ic) * 128;
  float* ob = out + ((size_t)(b * 1152 + 1024)) * (size_t)NQ + m;
  const float s = 1.f / 3.f;
#pragma unroll
  for (int c4 = 0; c4 < 32; c4 += 4) {
    int c = cg * 32 + c4;
    float4 v0 = *(const float4*)(f0 + c);
    float4 v1 = *(const float4*)(f1 + c);
    float4 v2 = *(const float4*)(f2 + c);
    ob[(size_t)(c + 0) * NQ] = ((v0.x + v1.x) + v2.x) * s;
    ob[(size_t)(c + 1) * NQ] = ((v0.y + v1.y) + v2.y) * s;
    ob[(size_t)(c + 2) * NQ] = ((v0.z + v1.z) + v2.z) * s;
    ob[(size_t)(c + 3) * NQ] = ((v0.w + v1.w) + v2.w) * s;
  }
}

extern "C" void kernel_launch(void* const* d_in, const int* in_sizes, int n_in,
                              void* d_out, int out_size, void* d_ws, size_t ws_size,
                              hipStream_t stream) {
  const float* pc  = (const float*)d_in[0];
  const float* qp  = (const float*)d_in[1];
  const float* W1  = (const float*)d_in[2];
  const float* b1  = (const float*)d_in[3];
  const float* W2  = (const float*)d_in[4];
  const float* b2  = (const float*)d_in[5];
  const float* G1  = (const float*)d_in[6];
  const float* g1b = (const float*)d_in[7];
  const float* G2  = (const float*)d_in[8];
  const float* g2b = (const float*)d_in[9];
  float* out = (float*)d_out;

  char* ws = (char*)d_ws;
  float*    lfT   = (float*)(ws + 0);              // 16,777,216 B  [B][N][128]
  float*    g1T   = (float*)(ws + 16777216);       // 33,554,432 B  [B][N][256]
  unsigned* gmaxK = (unsigned*)(ws + 50331648);    // 16,384 B      [B][1024]
  // KNN scratch overlaps g1T (dead after GEMM2; stream-ordered):
  double*   pd    = (double*)(ws + 16777216);      // 3,145,728 B   [32768][12] f64
  int*      pi    = (int*)(ws + 19922944);         // 1,572,864 B
  int*      ids   = (int*)(ws + 21495808);         // 524,288 B     [32768][4]

  k_init<<<16, 256, 0, stream>>>(gmaxK);
  k_local<<<128, 256, 0, stream>>>(pc, W1, b1, W2, b2, lfT);
  // GEMM1: [32768 x 128] * [256 x 128]^T -> g1T (relu)
  k_gemm<true><<<dim3(256, 2), 256, 0, stream>>>(lfT, G1, g1b, g1T, nullptr, 128, 256);
  // GEMM2: [32768 x 256] * [1024 x 256]^T -> column max only
  k_gemm<false><<<dim3(256, 8), 256, 0, stream>>>(g1T, G2, g2b, nullptr, gmaxK, 256, 1024);
  k_knn<<<512, 256, 0, stream>>>(pc, qp, pd, pi);
  k_merge<<<128, 256, 0, stream>>>(pd, pi, ids);
  k_bcast<<<32768, 256, 0, stream>>>(gmaxK, out);
  k_gather<<<512, 256, 0, stream>>>(lfT, ids, out);
}

// Round 3
// 340.120 us; speedup vs baseline: 1.4795x; 1.4795x over previous
//
#include <hip/hip_runtime.h>

#define NPTS 8192
#define NB 4
#define NQ 8192

using frag_ab = __attribute__((ext_vector_type(8))) short;   // 8 bf16 (4 VGPRs)
using f32x4   = __attribute__((ext_vector_type(4))) float;

// ---------- monotone float<->uint key for atomic max over floats ----------
__device__ __forceinline__ unsigned fkey(float f) {
  unsigned u = __float_as_uint(f);
  return (u & 0x80000000u) ? ~u : (u | 0x80000000u);
}
__device__ __forceinline__ float funkey(unsigned k) {
  unsigned u = (k & 0x80000000u) ? (k & 0x7fffffffu) : ~k;
  return __uint_as_float(u);
}
__device__ __forceinline__ unsigned short bf16rn(float f) {
  unsigned u = __float_as_uint(f);
  return (unsigned short)((u + 0x7fffu + ((u >> 16) & 1u)) >> 16);
}

// ---------- init gmax keys to 0 (== most-negative key) ----------
__global__ void k_init(unsigned* __restrict__ g) {
  g[blockIdx.x * 256 + threadIdx.x] = 0u;
}

// ---------- cast G2 weights f32 -> bf16 ----------
__global__ __launch_bounds__(256) void k_castW(const float* __restrict__ W,
                                               unsigned short* __restrict__ Wb) {
  int id = blockIdx.x * 256 + threadIdx.x;   // 0..65535, 4 elems each
  float4 v = *(const float4*)(W + (size_t)id * 4);
  unsigned short r0 = bf16rn(v.x), r1 = bf16rn(v.y), r2 = bf16rn(v.z), r3 = bf16rn(v.w);
  uint2 pk;
  pk.x = (unsigned)r0 | ((unsigned)r1 << 16);
  pk.y = (unsigned)r2 | ((unsigned)r3 << 16);
  *(uint2*)(Wb + (size_t)id * 4) = pk;
}

// ---------- local encoder: lfT[b][n][128] = relu(W2 relu(W1 p + b1) + b2) ----------
__global__ __launch_bounds__(256) void k_local(const float* __restrict__ pc,
    const float* __restrict__ W1, const float* __restrict__ b1,
    const float* __restrict__ W2, const float* __restrict__ b2,
    float* __restrict__ lfT) {
  __shared__ float sW1[192], sb1[64], sW2[8192], sb2[128];
  int t = threadIdx.x;
  if (t < 192) sW1[t] = W1[t];
  if (t < 64) sb1[t] = b1[t];
  if (t < 128) sb2[t] = b2[t];
  for (int i = t; i < 8192; i += 256) sW2[i] = W2[i];
  __syncthreads();

  int gid = blockIdx.x * 256 + t;        // b*N + n
  int b = gid >> 13;
  const float* base = pc + (size_t)b * 3 * NPTS + (gid & 8191);
  float x = base[0], y = base[NPTS], z = base[2 * NPTS];

  float h[64];
#pragma unroll
  for (int j = 0; j < 64; ++j) {
    float v = fmaf(sW1[j * 3 + 2], z, fmaf(sW1[j * 3 + 1], y, fmaf(sW1[j * 3], x, sb1[j])));
    h[j] = fmaxf(v, 0.f);
  }

  float* o = lfT + (size_t)gid * 128;
  for (int c = 0; c < 128; c += 4) {
    float a0 = sb2[c], a1 = sb2[c + 1], a2 = sb2[c + 2], a3 = sb2[c + 3];
#pragma unroll
    for (int j = 0; j < 64; j += 4) {
      float4 w0 = *(const float4*)&sW2[(c + 0) * 64 + j];
      float4 w1 = *(const float4*)&sW2[(c + 1) * 64 + j];
      float4 w2 = *(const float4*)&sW2[(c + 2) * 64 + j];
      float4 w3 = *(const float4*)&sW2[(c + 3) * 64 + j];
      a0 = fmaf(w0.x, h[j], fmaf(w0.y, h[j + 1], fmaf(w0.z, h[j + 2], fmaf(w0.w, h[j + 3], a0))));
      a1 = fmaf(w1.x, h[j], fmaf(w1.y, h[j + 1], fmaf(w1.z, h[j + 2], fmaf(w1.w, h[j + 3], a1))));
      a2 = fmaf(w2.x, h[j], fmaf(w2.y, h[j + 1], fmaf(w2.z, h[j + 2], fmaf(w2.w, h[j + 3], a2))));
      a3 = fmaf(w3.x, h[j], fmaf(w3.y, h[j + 1], fmaf(w3.z, h[j + 2], fmaf(w3.w, h[j + 3], a3))));
    }
    float4 r;
    r.x = fmaxf(a0, 0.f); r.y = fmaxf(a1, 0.f); r.z = fmaxf(a2, 0.f); r.w = fmaxf(a3, 0.f);
    *(float4*)&o[c] = r;
  }
}

// ---------- GEMM1 (f32): g1b16[m][n] = bf16(relu(lfT[m][:] . G1[n][:] + g1b[n])) ----------
__global__ __launch_bounds__(256) void k_gemm1(const float* __restrict__ A,
    const float* __restrict__ Bw, const float* __restrict__ bias,
    unsigned short* __restrict__ C) {
  const int Kdim = 128, Nw = 256;
  __shared__ float As[32][132];
  __shared__ float Bs[32][132];
  int t = threadIdx.x;
  int mBase = blockIdx.x * 128;
  int nBase = blockIdx.y * 128;
  int tx = t & 15, ty = t >> 4;
  float acc[8][8] = {};

  for (int kc = 0; kc < Kdim; kc += 32) {
    __syncthreads();
#pragma unroll
    for (int i = 0; i < 4; ++i) {
      int idx = t + i * 256;
      int r = idx >> 3;
      int k4 = (idx & 7) << 2;
      float4 v = *(const float4*)(A + (size_t)(mBase + r) * Kdim + kc + k4);
      As[k4 + 0][r] = v.x; As[k4 + 1][r] = v.y; As[k4 + 2][r] = v.z; As[k4 + 3][r] = v.w;
      float4 w = *(const float4*)(Bw + (size_t)(nBase + r) * Kdim + kc + k4);
      Bs[k4 + 0][r] = w.x; Bs[k4 + 1][r] = w.y; Bs[k4 + 2][r] = w.z; Bs[k4 + 3][r] = w.w;
    }
    __syncthreads();
#pragma unroll
    for (int kk = 0; kk < 32; ++kk) {
      float a[8], bv[8];
      *(float4*)&a[0] = *(const float4*)&As[kk][ty * 8];
      *(float4*)&a[4] = *(const float4*)&As[kk][ty * 8 + 4];
      *(float4*)&bv[0] = *(const float4*)&Bs[kk][tx * 8];
      *(float4*)&bv[4] = *(const float4*)&Bs[kk][tx * 8 + 4];
#pragma unroll
      for (int i = 0; i < 8; ++i)
#pragma unroll
        for (int j = 0; j < 8; ++j)
          acc[i][j] = fmaf(a[i], bv[j], acc[i][j]);
    }
  }

  float bb[8];
#pragma unroll
  for (int j = 0; j < 8; ++j) bb[j] = bias[nBase + tx * 8 + j];
#pragma unroll
  for (int i = 0; i < 8; ++i) {
    unsigned short* dst = C + (size_t)(mBase + ty * 8 + i) * Nw + nBase + tx * 8;
    uint4 pk;
    unsigned short r[8];
#pragma unroll
    for (int j = 0; j < 8; ++j) r[j] = bf16rn(fmaxf(acc[i][j] + bb[j], 0.f));
    pk.x = (unsigned)r[0] | ((unsigned)r[1] << 16);
    pk.y = (unsigned)r[2] | ((unsigned)r[3] << 16);
    pk.z = (unsigned)r[4] | ((unsigned)r[5] << 16);
    pk.w = (unsigned)r[6] | ((unsigned)r[7] << 16);
    *(uint4*)dst = pk;
  }
}

// ---------- GEMM2 (bf16 MFMA, no C store): column-max -> gmaxK ----------
// A: [32768][256] bf16 row-major; W: [1024][256] bf16 row-major.
// Block 128x128 tile, 4 waves (each 32 rows x 128 cols), K=256.
__global__ __launch_bounds__(256) void k_gmax(const unsigned short* __restrict__ A,
    const unsigned short* __restrict__ W, const float* __restrict__ bias,
    unsigned* __restrict__ gmaxK) {
  __shared__ unsigned smax[128];
  int t = threadIdx.x;
  int w = t >> 6, l = t & 63;
  int lr = l & 15, lg = l >> 4;
  int mBase = blockIdx.x * 128, nBase = blockIdx.y * 128;
  if (t < 128) smax[t] = 0u;
  __syncthreads();

  const unsigned short* arow = A + (size_t)(mBase + w * 32 + lr) * 256 + lg * 8;
  const unsigned short* wrow = W + (size_t)(nBase + lr) * 256 + lg * 8;

  f32x4 acc0[8] = {};
  f32x4 acc1[8] = {};
#pragma unroll
  for (int ko = 0; ko < 256; ko += 32) {
    frag_ab a0 = *(const frag_ab*)(arow + ko);
    frag_ab a1 = *(const frag_ab*)(arow + 16 * 256 + ko);
#pragma unroll
    for (int ni = 0; ni < 8; ++ni) {
      frag_ab bb = *(const frag_ab*)(wrow + (size_t)ni * 16 * 256 + ko);
      acc0[ni] = __builtin_amdgcn_mfma_f32_16x16x32_bf16(a0, bb, acc0[ni], 0, 0, 0);
      acc1[ni] = __builtin_amdgcn_mfma_f32_16x16x32_bf16(a1, bb, acc1[ni], 0, 0, 0);
    }
  }

#pragma unroll
  for (int ni = 0; ni < 8; ++ni) {
    float v = fmaxf(fmaxf(fmaxf(acc0[ni][0], acc0[ni][1]), fmaxf(acc0[ni][2], acc0[ni][3])),
                    fmaxf(fmaxf(acc1[ni][0], acc1[ni][1]), fmaxf(acc1[ni][2], acc1[ni][3])));
    v = fmaxf(v, __shfl_xor(v, 16));
    v = fmaxf(v, __shfl_xor(v, 32));
    if (lg == 0) atomicMax(&smax[ni * 16 + lr], fkey(v));
  }
  __syncthreads();
  if (t < 128) {
    float cm = funkey(smax[t]) + bias[nBase + t];
    atomicMax(&gmaxK[(mBase >> 13) * 1024 + nBase + t], fkey(cm));
  }
}

// ---------- KNN phase A ----------
// e-space: for fixed query, d = qq - 2 dot + pp orders identically to e = pp - 2 dot.
// f64 => ordering matches numpy-f64 reference (band ~1e-16).
// Grid: b(4) x qblock(16, 512 queries) x chunk(16, 512 candidates). 2 queries/thread.
#define INSERT(e, n, D0, D1, D2, I0, I1, I2)                         \
  if (e < D2) {                                                      \
    if (e < D1) {                                                    \
      D2 = D1; I2 = I1;                                              \
      if (e < D0) { D1 = D0; I1 = I0; D0 = e; I0 = n; }              \
      else        { D1 = e;  I1 = n; }                               \
    } else { D2 = e; I2 = n; }                                       \
  }

__global__ __launch_bounds__(256) void k_knn(const float* __restrict__ pc,
    const float* __restrict__ qp, double* __restrict__ pd, int* __restrict__ pi) {
  __shared__ double4 pts[512];
  int bid = blockIdx.x;
  int cc = bid & 15, qb = (bid >> 4) & 15, b = bid >> 8;
  int t = threadIdx.x;
  int n0 = cc * 512;
  const float* pb = pc + (size_t)b * 3 * NPTS;
  for (int i = t; i < 512; i += 256) {
    double x = (double)pb[n0 + i], y = (double)pb[NPTS + n0 + i], z = (double)pb[2 * NPTS + n0 + i];
    pts[i] = make_double4(x, y, z, fma(x, x, fma(y, y, z * z)));
  }
  __syncthreads();

  int mA = qb * 512 + t;
  int mB = mA + 256;
  const float* qbase = qp + (size_t)b * 3 * NPTS;
  double tax = -2.0 * (double)qbase[mA], tay = -2.0 * (double)qbase[NPTS + mA],
         taz = -2.0 * (double)qbase[2 * NPTS + mA];
  double tbx = -2.0 * (double)qbase[mB], tby = -2.0 * (double)qbase[NPTS + mB],
         tbz = -2.0 * (double)qbase[2 * NPTS + mB];

  double a0 = 1e300, a1 = 1e300, a2 = 1e300;
  double b0 = 1e300, b1 = 1e300, b2 = 1e300;
  int ai0 = 0, ai1 = 0, ai2 = 0, bi0 = 0, bi1 = 0, bi2 = 0;

  for (int i = 0; i < 512; i += 4) {
    double4 p0 = pts[i], p1 = pts[i + 1], p2 = pts[i + 2], p3 = pts[i + 3];
    double eA0 = fma(p0.x, tax, fma(p0.y, tay, fma(p0.z, taz, p0.w)));
    double eA1 = fma(p1.x, tax, fma(p1.y, tay, fma(p1.z, taz, p1.w)));
    double eA2 = fma(p2.x, tax, fma(p2.y, tay, fma(p2.z, taz, p2.w)));
    double eA3 = fma(p3.x, tax, fma(p3.y, tay, fma(p3.z, taz, p3.w)));
    double eB0 = fma(p0.x, tbx, fma(p0.y, tby, fma(p0.z, tbz, p0.w)));
    double eB1 = fma(p1.x, tbx, fma(p1.y, tby, fma(p1.z, tbz, p1.w)));
    double eB2 = fma(p2.x, tbx, fma(p2.y, tby, fma(p2.z, tbz, p2.w)));
    double eB3 = fma(p3.x, tbx, fma(p3.y, tby, fma(p3.z, tbz, p3.w)));
    double mnA = fmin(fmin(eA0, eA1), fmin(eA2, eA3));
    double mnB = fmin(fmin(eB0, eB1), fmin(eB2, eB3));
    if (mnA < a2) {
      int n = n0 + i;
      INSERT(eA0, n,     a0, a1, a2, ai0, ai1, ai2);
      INSERT(eA1, n + 1, a0, a1, a2, ai0, ai1, ai2);
      INSERT(eA2, n + 2, a0, a1, a2, ai0, ai1, ai2);
      INSERT(eA3, n + 3, a0, a1, a2, ai0, ai1, ai2);
    }
    if (mnB < b2) {
      int n = n0 + i;
      INSERT(eB0, n,     b0, b1, b2, bi0, bi1, bi2);
      INSERT(eB1, n + 1, b0, b1, b2, bi0, bi1, bi2);
      INSERT(eB2, n + 2, b0, b1, b2, bi0, bi1, bi2);
      INSERT(eB3, n + 3, b0, b1, b2, bi0, bi1, bi2);
    }
  }

  {
    int q = b * NQ + mA;
    double* pdq = pd + (size_t)q * 48 + cc * 3;
    int* piq = pi + (size_t)q * 48 + cc * 3;
    pdq[0] = a0; pdq[1] = a1; pdq[2] = a2;
    piq[0] = ai0; piq[1] = ai1; piq[2] = ai2;
  }
  {
    int q = b * NQ + mB;
    double* pdq = pd + (size_t)q * 48 + cc * 3;
    int* piq = pi + (size_t)q * 48 + cc * 3;
    pdq[0] = b0; pdq[1] = b1; pdq[2] = b2;
    piq[0] = bi0; piq[1] = bi1; piq[2] = bi2;
  }
}

// ---------- KNN phase B: merge 16 chunk-partials (chunk order => index order, stable) ----------
__global__ __launch_bounds__(256) void k_merge(const double* __restrict__ pd,
    const int* __restrict__ pi, int* __restrict__ ids) {
  int q = blockIdx.x * 256 + threadIdx.x;
  double d0 = 1e300, d1 = 1e300, d2v = 1e300;
  int i0 = 0, i1 = 0, i2 = 0;
#pragma unroll
  for (int j = 0; j < 48; ++j) {
    double d = pd[(size_t)q * 48 + j];
    int n = pi[(size_t)q * 48 + j];
    INSERT(d, n, d0, d1, d2v, i0, i1, i2);
  }
  ids[q * 4 + 0] = i0; ids[q * 4 + 1] = i1; ids[q * 4 + 2] = i2;
}

// ---------- broadcast gmax into out channels [0,1024) ----------
__global__ __launch_bounds__(256) void k_bcast(const unsigned* __restrict__ gmaxK,
                                               float* __restrict__ out) {
  int id = blockIdx.x * 256 + threadIdx.x;   // float4 index
  int m4 = id & 2047;
  int c = (id >> 11) & 1023;
  int b = id >> 21;
  float v = funkey(gmaxK[b * 1024 + c]);
  *(float4*)(out + ((size_t)(b * 1152 + c) << 13) + (m4 << 2)) = make_float4(v, v, v, v);
}

// ---------- gather: out channels [1024,1152) = mean of 3 NN local feats ----------
__global__ __launch_bounds__(256) void k_gather(const float* __restrict__ lfT,
    const int* __restrict__ ids, float* __restrict__ out) {
  int bid = blockIdx.x;
  int b = bid >> 7, mb = bid & 127;
  int t = threadIdx.x;
  int m = mb * 64 + (t & 63);
  int cg = t >> 6;
  int q = b * NQ + m;
  int ia = ids[q * 4 + 0], ib = ids[q * 4 + 1], ic = ids[q * 4 + 2];
  const float* f0 = lfT + ((size_t)b * NPTS + ia) * 128;
  const float* f1 = lfT + ((size_t)b * NPTS + ib) * 128;
  const float* f2 = lfT + ((size_t)b * NPTS + ic) * 128;
  float* ob = out + ((size_t)(b * 1152 + 1024)) * (size_t)NQ + m;
  const float s = 1.f / 3.f;
#pragma unroll
  for (int c4 = 0; c4 < 32; c4 += 4) {
    int c = cg * 32 + c4;
    float4 v0 = *(const float4*)(f0 + c);
    float4 v1 = *(const float4*)(f1 + c);
    float4 v2 = *(const float4*)(f2 + c);
    ob[(size_t)(c + 0) * NQ] = ((v0.x + v1.x) + v2.x) * s;
    ob[(size_t)(c + 1) * NQ] = ((v0.y + v1.y) + v2.y) * s;
    ob[(size_t)(c + 2) * NQ] = ((v0.z + v1.z) + v2.z) * s;
    ob[(size_t)(c + 3) * NQ] = ((v0.w + v1.w) + v2.w) * s;
  }
}

extern "C" void kernel_launch(void* const* d_in, const int* in_sizes, int n_in,
                              void* d_out, int out_size, void* d_ws, size_t ws_size,
                              hipStream_t stream) {
  const float* pc  = (const float*)d_in[0];
  const float* qp  = (const float*)d_in[1];
  const float* W1  = (const float*)d_in[2];
  const float* b1  = (const float*)d_in[3];
  const float* W2  = (const float*)d_in[4];
  const float* b2  = (const float*)d_in[5];
  const float* G1  = (const float*)d_in[6];
  const float* g1b = (const float*)d_in[7];
  const float* G2  = (const float*)d_in[8];
  const float* g2b = (const float*)d_in[9];
  float* out = (float*)d_out;

  char* ws = (char*)d_ws;
  float*          lfT   = (float*)(ws + 0);               // 16,777,216 B  [B][N][128] f32
  unsigned short* g1b16 = (unsigned short*)(ws + 16777216); // 16,777,216 B [32768][256] bf16
  unsigned short* G2b16 = (unsigned short*)(ws + 33554432); // 524,288 B   [1024][256] bf16
  unsigned*       gmaxK = (unsigned*)(ws + 34078720);      // 16,384 B     [B][1024]
  // KNN scratch overlaps g1b16 (dead after k_gmax; stream-ordered):
  double*         pd    = (double*)(ws + 16777216);        // 12,582,912 B [32768][48] f64
  int*            pi    = (int*)(ws + 34095104);           // 6,291,456 B  [32768][48]
  int*            ids   = (int*)(ws + 40386560);           // 524,288 B    [32768][4]

  k_init<<<16, 256, 0, stream>>>(gmaxK);
  k_castW<<<256, 256, 0, stream>>>(G2, G2b16);
  k_local<<<128, 256, 0, stream>>>(pc, W1, b1, W2, b2, lfT);
  k_gemm1<<<dim3(256, 2), 256, 0, stream>>>(lfT, G1, g1b, g1b16);
  k_gmax<<<dim3(256, 8), 256, 0, stream>>>(g1b16, G2b16, g2b, gmaxK);
  k_knn<<<1024, 256, 0, stream>>>(pc, qp, pd, pi);
  k_merge<<<128, 256, 0, stream>>>(pd, pi, ids);
  k_bcast<<<32768, 256, 0, stream>>>(gmaxK, out);
  k_gather<<<512, 256, 0, stream>>>(lfT, ids, out);
}